// Round 6
// baseline (108.535 us; speedup 1.0000x reference)
//
#include <hip/hip_runtime.h>
#include <hip/hip_bf16.h>
#include <math.h>

// B=8, T=2048, C=1024, H=64.
// out = softmax( (X Wq^T)(X Wk^T)^T * C^-0.5, key mask ) @ (X Wv^T)
//
// Round 6 = Round 5 resubmitted (round-5 bench died on infra, no signal):
//  * attn: kvsplit=4, 256-thr blocks (1 q-subtile x 4 kv-quarters), grid 1024
//    -> 4 blocks/CU, 16 waves/CU (was 8). Deferred rescale (THR=8) skips the
//    O-rescale + alpha broadcast on most tiles; when needed, alpha broadcast
//    via per-wave LDS f32x4 (1 write + 1 broadcast read) not 4 bpermutes.
//    4-way merge (m,l,O) via LDS at the end; O rows at stride-17 (bank-clean).
//  * proj: W prefetch 4-buffer rotation (3-iter slack covers L2 latency).

#define T_SEQ 2048
#define EMB 1024
#define HS 64
#define NB 8

typedef __attribute__((ext_vector_type(8))) short short8;
typedef __attribute__((ext_vector_type(4))) float f32x4;
typedef __attribute__((ext_vector_type(2))) unsigned int uint2_t;
typedef unsigned short ushort_t;

static __device__ inline ushort_t f2bf(float f) {
  union { float f; unsigned u; } v; v.f = f;
  unsigned r = v.u + 0x7FFF + ((v.u >> 16) & 1);  // RNE
  return (ushort_t)(r >> 16);
}
static __device__ inline unsigned pk2(float a, float b) {
  return (unsigned)f2bf(a) | ((unsigned)f2bf(b) << 16);
}

// ---------------- k1: W conversion (48 blocks x 256 thr) ----------------
__global__ __launch_bounds__(256) void convw_kernel(
    const float* __restrict__ Wq, const float* __restrict__ Wk,
    const float* __restrict__ Wv, ushort_t* __restrict__ Wb) {
  const int m = blockIdx.x >> 4;
  const int blk = blockIdx.x & 15;
  const float* src = (m == 0) ? Wq : (m == 1) ? Wk : Wv;
  const float scale = (m == 0) ? 0.03125f : 1.0f;  // fold C^-0.5 into Wq
  const int base = blk * 4096 + threadIdx.x * 16;
  ushort_t* dst = Wb + m * 65536;
  ushort_t tmp[16];
#pragma unroll
  for (int j = 0; j < 4; ++j) {
    float4 x = *(const float4*)(src + base + j * 4);
    tmp[j * 4 + 0] = f2bf(x.x * scale);
    tmp[j * 4 + 1] = f2bf(x.y * scale);
    tmp[j * 4 + 2] = f2bf(x.z * scale);
    tmp[j * 4 + 3] = f2bf(x.w * scale);
  }
  *(short8*)(dst + base) = *(short8*)tmp;
  *(short8*)(dst + base + 8) = *(short8*)(tmp + 8);
}

// ---------------- k2: projections (512 blocks x 256 thr) ----------------
// Block = 32 X-rows (one batch). X staged whole (64KB, XOR swizzle), 1 barrier.
// Wave w owns 48 out cols (ht=3w+t; m=ht>>2: 0=Q 1=K 2=V). W prefetch 4-deep.
__global__ __launch_bounds__(256, 2) void proj_kernel(
    const float* __restrict__ X, const ushort_t* __restrict__ Wb,
    ushort_t* __restrict__ Qb, ushort_t* __restrict__ Kb,
    ushort_t* __restrict__ Vtb) {
  __shared__ __align__(16) ushort_t Xs[32 * 1024];  // 64KB
  const int tid = threadIdx.x;
  const int lane = tid & 63, w = tid >> 6;
  const int l15 = lane & 15, hi = lane >> 4;
  const long rbase = (long)blockIdx.x * 32;

  const ushort_t* Wrow[3];
#pragma unroll
  for (int t = 0; t < 3; ++t) {
    const int ht = 3 * w + t, m = ht >> 2, hs = ht & 3;
    Wrow[t] = Wb + m * 65536 + (hs * 16 + l15) * 1024 + hi * 8;
  }

  short8 wfA[6], wfB[6], wfC[6], wfD[6];  // named 4-deep rotation (rule #20)
  auto loadw = [&](short8 (&dst)[6], int s) {
#pragma unroll
    for (int t = 0; t < 3; ++t) {
      dst[2 * t + 0] = *(const short8*)(Wrow[t] + s * 64);
      dst[2 * t + 1] = *(const short8*)(Wrow[t] + s * 64 + 32);
    }
  };
  loadw(wfA, 0); loadw(wfB, 1); loadw(wfC, 2);

  // stage whole X tile (fp32 -> bf16, XOR-swizzled rows)
  {
    const int srow = tid >> 3, scb = (tid & 7) * 16;
    const int sw = (srow & 7) << 4;
    const float* Xg = X + (rbase + srow) * EMB + (tid & 7) * 8;
    char* Xrow = (char*)Xs + srow * 2048;
#pragma unroll
    for (int s = 0; s < 16; ++s) {
      float4 a = *(const float4*)(Xg + s * 64);
      float4 b = *(const float4*)(Xg + s * 64 + 4);
      ushort_t tmp[8];
      tmp[0] = f2bf(a.x); tmp[1] = f2bf(a.y);
      tmp[2] = f2bf(a.z); tmp[3] = f2bf(a.w);
      tmp[4] = f2bf(b.x); tmp[5] = f2bf(b.y);
      tmp[6] = f2bf(b.z); tmp[7] = f2bf(b.w);
      *(short8*)(Xrow + ((scb + s * 128) ^ sw)) = *(short8*)tmp;
    }
  }
  __syncthreads();

  f32x4 acc[2][3];
#pragma unroll
  for (int rt = 0; rt < 2; ++rt)
#pragma unroll
    for (int t = 0; t < 3; ++t) acc[rt][t] = (f32x4){0.f, 0.f, 0.f, 0.f};

  const int swA = (l15 & 7) << 4;
  auto body = [&](int s, short8 (&cur)[6], short8 (&pre)[6]) {
    if (s + 3 < 16) loadw(pre, s + 3);
#pragma unroll
    for (int rt = 0; rt < 2; ++rt) {
      const char* Xrow = (const char*)Xs + (rt * 16 + l15) * 2048;
      short8 a0 = *(const short8*)(Xrow + ((s * 128 + hi * 16) ^ swA));
      short8 a1 = *(const short8*)(Xrow + ((s * 128 + 64 + hi * 16) ^ swA));
#pragma unroll
      for (int t = 0; t < 3; ++t) {
        acc[rt][t] = __builtin_amdgcn_mfma_f32_16x16x32_bf16(
            a0, cur[2 * t + 0], acc[rt][t], 0, 0, 0);
        acc[rt][t] = __builtin_amdgcn_mfma_f32_16x16x32_bf16(
            a1, cur[2 * t + 1], acc[rt][t], 0, 0, 0);
      }
    }
  };
#pragma unroll
  for (int s4 = 0; s4 < 16; s4 += 4) {
    body(s4 + 0, wfA, wfD);
    body(s4 + 1, wfB, wfA);
    body(s4 + 2, wfC, wfB);
    body(s4 + 3, wfD, wfC);
  }

  // epilogue: D col=l15, row=4*hi+reg. Q/K row-major [B*T][64];
  // V transposed PER BATCH: Vtb[b][h][t]
  const long bblk = rbase >> 11;
  const long tb0 = rbase & 2047;
  ushort_t* outs[2] = {Qb, Kb};
#pragma unroll
  for (int rt = 0; rt < 2; ++rt)
#pragma unroll
    for (int t = 0; t < 3; ++t) {
      const int ht = 3 * w + t, m = ht >> 2, hs = ht & 3;
      const int h = hs * 16 + l15;
      if (m < 2) {
#pragma unroll
        for (int r = 0; r < 4; ++r) {
          const long row = rbase + rt * 16 + 4 * hi + r;
          outs[m][row * 64 + h] = f2bf(acc[rt][t][r]);
        }
      } else {
        const long tloc = tb0 + rt * 16 + 4 * hi;
        uint2_t v;
        v.x = pk2(acc[rt][t][0], acc[rt][t][1]);
        v.y = pk2(acc[rt][t][2], acc[rt][t][3]);
        *(uint2_t*)(Vtb + bblk * (long)HS * T_SEQ + (long)h * T_SEQ + tloc) = v;
      }
    }
}

// ---------------- k3: attention (1024 blocks x 256 thr) ----------------
// Block = 16 queries x full KV; wave w = kv quarter (512 keys = 8 tiles).
__global__ __launch_bounds__(256, 4) void attn_kernel(
    const ushort_t* __restrict__ Qb, const ushort_t* __restrict__ Kb,
    const ushort_t* __restrict__ Vtb, const int* __restrict__ mask,
    float* __restrict__ out) {
  __shared__ __align__(16) float biasLds[T_SEQ];   // 8KB
  __shared__ __align__(16) ushort_t Ps[4 * 1024];  // 8KB (2KB per wave)
  __shared__ __align__(16) float alphaArr[4 * 16];
  __shared__ __align__(16) float mM[4 * 16];
  __shared__ __align__(16) float mL[4 * 16];
  __shared__ float mO[3 * 64 * 17];                // 12.75KB, stride 17

  const int tid = threadIdx.x;
  const int lane = tid & 63, w = tid >> 6;  // w = kv quarter
  const int l15 = lane & 15, hi = lane >> 4;
  const int id = blockIdx.x;
  const int b = id & 7;                     // batch -> XCD (L2 locality)
  const int q0 = (id >> 3) * 16;

  // stage mask bias once (256 thr x 8 ints)
  {
    const int* mp = mask + b * T_SEQ + tid * 8;
    int4 m0 = *(const int4*)(mp);
    int4 m1 = *(const int4*)(mp + 4);
    float4 b0 = {m0.x ? -1e30f : 0.f, m0.y ? -1e30f : 0.f,
                 m0.z ? -1e30f : 0.f, m0.w ? -1e30f : 0.f};
    float4 b1 = {m1.x ? -1e30f : 0.f, m1.y ? -1e30f : 0.f,
                 m1.z ? -1e30f : 0.f, m1.w ? -1e30f : 0.f};
    *(float4*)(biasLds + tid * 8) = b0;
    *(float4*)(biasLds + tid * 8 + 4) = b1;
  }

  // Q fragments (16 queries, shared by all 4 waves)
  const ushort_t* Qrow = Qb + (long)(b * T_SEQ + q0 + l15) * 64;
  const short8 qf0 = *(const short8*)(Qrow + hi * 8);
  const short8 qf1 = *(const short8*)(Qrow + 32 + hi * 8);

  const ushort_t* Kg = Kb + (long)b * T_SEQ * 64;
  const ushort_t* Vg = Vtb + (long)b * HS * T_SEQ;
  const int k0 = w * 512;  // this wave's key range

  const ushort_t* kbase = Kg + ((long)k0 + l15) * 64 + hi * 8;
  const ushort_t* vbase = Vg + (long)l15 * T_SEQ + k0 + hi * 8;

  short8 kfA[8], kfB[8];  // named double buffers (rule #20)
#pragma unroll
  for (int kt = 0; kt < 4; ++kt) {
    kfA[kt * 2 + 0] = *(const short8*)(kbase + kt * 1024);
    kfA[kt * 2 + 1] = *(const short8*)(kbase + kt * 1024 + 32);
  }

  f32x4 O[4];
#pragma unroll
  for (int ht = 0; ht < 4; ++ht) O[ht] = (f32x4){0.f, 0.f, 0.f, 0.f};
  float mrow = -1e30f, lsum = 0.f;

  char* prow = (char*)Ps + w * 2048 + l15 * 128;
  const int sw = (l15 & 7) << 4;

  __syncthreads();  // bias visible

  auto tile_step = [&](const int t, short8 (&kcur)[8], short8 (&knxt)[8]) {
    // V fragments (issue early; consumed after softmax)
    short8 vf[8];
#pragma unroll
    for (int ht = 0; ht < 4; ++ht) {
      vf[ht * 2 + 0] = *(const short8*)(vbase + (long)ht * 16 * T_SEQ + t * 64);
      vf[ht * 2 + 1] = *(const short8*)(vbase + (long)ht * 16 * T_SEQ + t * 64 + 32);
    }

    // S^T = K.Q^T : col(l15)=query, row(4hi+r)=key
    f32x4 s[4];
    __builtin_amdgcn_s_setprio(1);
#pragma unroll
    for (int kt = 0; kt < 4; ++kt) {
      f32x4 z = {0.f, 0.f, 0.f, 0.f};
      s[kt] = __builtin_amdgcn_mfma_f32_16x16x32_bf16(kcur[kt * 2 + 0], qf0, z, 0, 0, 0);
      s[kt] = __builtin_amdgcn_mfma_f32_16x16x32_bf16(kcur[kt * 2 + 1], qf1, s[kt], 0, 0, 0);
    }
    __builtin_amdgcn_s_setprio(0);

    if (t < 7) {  // prefetch next K tile
      const ushort_t* kb2 = kbase + (long)(t + 1) * 4096;
#pragma unroll
      for (int kt = 0; kt < 4; ++kt) {
        knxt[kt * 2 + 0] = *(const short8*)(kb2 + kt * 1024);
        knxt[kt * 2 + 1] = *(const short8*)(kb2 + kt * 1024 + 32);
      }
    }

    // mask bias
    const float* bl = biasLds + k0 + t * 64;
#pragma unroll
    for (int kt = 0; kt < 4; ++kt) s[kt] += *(const f32x4*)(bl + kt * 16 + hi * 4);

    // tile max for query l15 (keys spread over hi groups)
    float mt = -1e30f;
#pragma unroll
    for (int kt = 0; kt < 4; ++kt)
#pragma unroll
      for (int r = 0; r < 4; ++r) mt = fmaxf(mt, s[kt][r]);
    mt = fmaxf(mt, __shfl_xor(mt, 16, 64));
    mt = fmaxf(mt, __shfl_xor(mt, 32, 64));

    // deferred rescale (T13): skip alpha pass unless max grew > THR
    const bool skip = __all(mt <= mrow + 8.0f);
    float mnew = mrow;
    if (!skip) {
      mnew = fmaxf(mrow, mt);
      const float alpha = __expf(mrow - mnew);
      if (lane < 16) alphaArr[w * 16 + l15] = alpha;
      lsum *= alpha;
      mrow = mnew;
    }

    float psum = 0.f;
#pragma unroll
    for (int kt = 0; kt < 4; ++kt) {
      const float p0 = __expf(s[kt][0] - mnew);
      const float p1 = __expf(s[kt][1] - mnew);
      const float p2 = __expf(s[kt][2] - mnew);
      const float p3 = __expf(s[kt][3] - mnew);
      psum += (p0 + p1) + (p2 + p3);
      const int a0 = (kt * 32 + hi * 8) ^ sw;
      *(unsigned*)(prow + a0) = pk2(p0, p1);
      *(unsigned*)(prow + a0 + 4) = pk2(p2, p3);
    }
    lsum += psum;

    if (!skip) {  // O rescale: alpha for queries 4hi+0..3 via LDS broadcast
      const f32x4 av = *(const f32x4*)(alphaArr + w * 16 + 4 * hi);
#pragma unroll
      for (int ht = 0; ht < 4; ++ht) O[ht] *= av;
    }

    // PV: A = P rows (q=l15), B = V^T rows (h)
    short8 pa0 = *(const short8*)(prow + ((hi * 16) ^ sw));
    short8 pa1 = *(const short8*)(prow + ((64 + hi * 16) ^ sw));
    __builtin_amdgcn_s_setprio(1);
#pragma unroll
    for (int ht = 0; ht < 4; ++ht) {
      O[ht] = __builtin_amdgcn_mfma_f32_16x16x32_bf16(pa0, vf[ht * 2 + 0], O[ht], 0, 0, 0);
      O[ht] = __builtin_amdgcn_mfma_f32_16x16x32_bf16(pa1, vf[ht * 2 + 1], O[ht], 0, 0, 0);
    }
    __builtin_amdgcn_s_setprio(0);
  };

#pragma unroll
  for (int t = 0; t < 8; t += 2) {
    tile_step(t, kfA, kfB);
    tile_step(t + 1, kfB, kfA);
  }

  // per-query l (reduce over hi groups)
  lsum += __shfl_xor(lsum, 16, 64);
  lsum += __shfl_xor(lsum, 32, 64);

  // 4-way merge across kv quarters
  if (lane < 16) {
    mM[w * 16 + l15] = mrow;
    mL[w * 16 + l15] = lsum;
  }
  if (w > 0) {
    float* mo = mO + (w - 1) * 64 * 17 + lane * 17;
#pragma unroll
    for (int ht = 0; ht < 4; ++ht)
#pragma unroll
      for (int r = 0; r < 4; ++r) mo[ht * 4 + r] = O[ht][r];
  }
  __syncthreads();
  if (w == 0) {
    f32x4 mv0 = *(const f32x4*)(mM + 0 * 16 + 4 * hi);
    f32x4 mv1 = *(const f32x4*)(mM + 1 * 16 + 4 * hi);
    f32x4 mv2 = *(const f32x4*)(mM + 2 * 16 + 4 * hi);
    f32x4 mv3 = *(const f32x4*)(mM + 3 * 16 + 4 * hi);
    f32x4 mtot;
#pragma unroll
    for (int r = 0; r < 4; ++r)
      mtot[r] = fmaxf(fmaxf(mv0[r], mv1[r]), fmaxf(mv2[r], mv3[r]));
    f32x4 a0v, a1v, a2v, a3v;
#pragma unroll
    for (int r = 0; r < 4; ++r) {
      a0v[r] = __expf(mv0[r] - mtot[r]);
      a1v[r] = __expf(mv1[r] - mtot[r]);
      a2v[r] = __expf(mv2[r] - mtot[r]);
      a3v[r] = __expf(mv3[r] - mtot[r]);
    }
    f32x4 lv0 = *(const f32x4*)(mL + 0 * 16 + 4 * hi);
    f32x4 lv1 = *(const f32x4*)(mL + 1 * 16 + 4 * hi);
    f32x4 lv2 = *(const f32x4*)(mL + 2 * 16 + 4 * hi);
    f32x4 lv3 = *(const f32x4*)(mL + 3 * 16 + 4 * hi);
    f32x4 inv;
#pragma unroll
    for (int r = 0; r < 4; ++r)
      inv[r] = 1.0f / (lv0[r] * a0v[r] + lv1[r] * a1v[r] +
                       lv2[r] * a2v[r] + lv3[r] * a3v[r]);

    float* ob = out + (long)(b * T_SEQ + q0) * 64;
#pragma unroll
    for (int ht = 0; ht < 4; ++ht) {
      f32x4 acc = O[ht] * a0v;
      const float* mo1 = mO + 0 * 64 * 17 + lane * 17 + ht * 4;
      const float* mo2 = mO + 1 * 64 * 17 + lane * 17 + ht * 4;
      const float* mo3 = mO + 2 * 64 * 17 + lane * 17 + ht * 4;
#pragma unroll
      for (int r = 0; r < 4; ++r)
        acc[r] += mo1[r] * a1v[r] + mo2[r] * a2v[r] + mo3[r] * a3v[r];
      acc *= inv;
#pragma unroll
      for (int r = 0; r < 4; ++r)
        ob[(4 * hi + r) * 64 + ht * 16 + l15] = acc[r];
    }
  }
}

// ---------------- launch ----------------
extern "C" void kernel_launch(void* const* d_in, const int* in_sizes, int n_in,
                              void* d_out, int out_size, void* d_ws, size_t ws_size,
                              hipStream_t stream) {
  const float* X  = (const float*)d_in[0];
  const float* Wq = (const float*)d_in[1];
  const float* Wk = (const float*)d_in[2];
  const float* Wv = (const float*)d_in[3];
  const int* mask = (const int*)d_in[4];
  float* outp = (float*)d_out;

  const long NT = (long)NB * T_SEQ * HS;
  ushort_t* wsb = (ushort_t*)d_ws;
  ushort_t* Qb  = wsb;            // 2 MB
  ushort_t* Kb  = wsb + NT;       // 2 MB
  ushort_t* Vtb = wsb + 2 * NT;   // 2 MB (per-batch transposed V)
  ushort_t* Wb  = wsb + 3 * NT;   // 384 KB

  convw_kernel<<<48, 256, 0, stream>>>(Wq, Wk, Wv, Wb);
  proj_kernel<<<(NB * T_SEQ) / 32, 256, 0, stream>>>(X, Wb, Qb, Kb, Vtb);
  attn_kernel<<<1024, 256, 0, stream>>>(Qb, Kb, Vtb, mask, outp);
}